// Round 1
// baseline (1929.762 us; speedup 1.0000x reference)
//
#include <hip/hip_runtime.h>
#include <hip/hip_bf16.h>

#define N_ATOMS 100000
#define N_PAIRS 2000000
#define N_EMB 30
#define N_DIST 100
#define N_HID 60

#define EBLOCKS 1024
#define WPB 4                       // waves per block
#define NWAVES (EBLOCKS * WPB)      // 4096

__device__ __forceinline__ float fast_tanh(float x) {
    // tanh(x) = 1 - 2/(exp(2x)+1); saturates correctly for large |x|
    float e = __expf(2.0f * x);
    return 1.0f - 2.0f / (e + 1.0f);
}

// ---------------- Kernel A: per-atom hidden + output init ----------------
// out[n,f] = af[n,f] - tanh( (b_df * ah[n]) @ W_fc )[f]
// ah[n,h]  = b_cf[h] + sum_k af[n,k] * W_cf[k,h]
__global__ __launch_bounds__(256) void atom_kernel(
    const float* __restrict__ af, const float* __restrict__ W_cf,
    const float* __restrict__ W_fc, const float* __restrict__ b_cf,
    const float* __restrict__ b_df, float* __restrict__ ah_out,
    float* __restrict__ out)
{
    __shared__ __align__(16) float ah_lds[WPB][N_HID];
    const int wave = threadIdx.x >> 6;
    const int lane = threadIdx.x & 63;
    const int n = blockIdx.x * WPB + wave;   // grid sized so n < N_ATOMS always

    float ahv = 0.f;
    if (lane < N_HID) {
        ahv = b_cf[lane];
        #pragma unroll
        for (int k = 0; k < N_EMB; ++k)
            ahv = fmaf(af[(size_t)n * N_EMB + k], W_cf[k * N_HID + lane], ahv);
        ah_out[(size_t)n * N_HID + lane] = ahv;
        ah_lds[wave][lane] = ahv * b_df[lane];
    }
    __syncthreads();
    if (lane < N_EMB) {
        float s = 0.f;
        #pragma unroll
        for (int h = 0; h < N_HID; ++h)
            s = fmaf(ah_lds[wave][h], W_fc[h * N_EMB + lane], s);
        out[(size_t)n * N_EMB + lane] =
            af[(size_t)n * N_EMB + lane] - fast_tanh(s);
    }
}

// ---------------- Kernel B: per-edge compute + segment-sum ----------------
__global__ __launch_bounds__(256) void edge_kernel(
    const float* __restrict__ dist,
    const int* __restrict__ mi, const int* __restrict__ mj,
    const float* __restrict__ W_df, const float* __restrict__ W_fc,
    const float* __restrict__ b_df, const float* __restrict__ ah,
    float* out)
{
    // W_dfT stride 100 words = 25 float4 (odd) -> conflict-free b128 reads
    __shared__ __align__(16) float WdfT[N_HID][N_DIST];   // 24000 B
    __shared__ __align__(16) float WfcT[N_EMB][68];       // stride 17 f4 (odd), 8160 B
    __shared__ __align__(16) float dbuf[WPB][N_DIST];     // 1600 B
    __shared__ __align__(16) float tbuf[WPB][N_HID];      // 960 B
    __shared__ float bdf_lds[N_HID];

    const int wave = threadIdx.x >> 6;
    const int lane = threadIdx.x & 63;

    for (int idx = threadIdx.x; idx < N_DIST * N_HID; idx += 256) {
        int k = idx / N_HID, h = idx % N_HID;
        WdfT[h][k] = W_df[idx];
    }
    for (int idx = threadIdx.x; idx < N_HID * N_EMB; idx += 256) {
        int h = idx / N_EMB, f = idx % N_EMB;
        WfcT[f][h] = W_fc[idx];
    }
    if (threadIdx.x < N_HID) bdf_lds[threadIdx.x] = b_df[threadIdx.x];
    __syncthreads();

    const int gw = blockIdx.x * WPB + wave;               // 0..4095
    const int per = (N_PAIRS + NWAVES - 1) / NWAVES;      // 489
    const int e0 = gw * per;
    const int e1 = min(e0 + per, N_PAIRS);

    float acc = 0.f;     // lanes f<30: running segment sum
    int cur_i = -1;

    for (int it = 0; it < per; ++it) {   // uniform trip count (block barrier inside)
        const int e = e0 + it;
        const bool active = (e < e1);

        if (active && lane < 25) {
            float4 v = ((const float4*)(dist + (size_t)e * N_DIST))[lane];
            ((float4*)dbuf[wave])[lane] = v;
        }
        __syncthreads();

        if (active && lane < N_HID) {
            float dh = bdf_lds[lane];
            const float4* wrow = (const float4*)WdfT[lane];
            const float4* drow = (const float4*)dbuf[wave];
            #pragma unroll
            for (int c = 0; c < 25; ++c) {
                float4 dv = drow[c];
                float4 wv = wrow[c];
                dh = fmaf(dv.x, wv.x, dh);
                dh = fmaf(dv.y, wv.y, dh);
                dh = fmaf(dv.z, wv.z, dh);
                dh = fmaf(dv.w, wv.w, dh);
            }
            const int j = mj[e];
            tbuf[wave][lane] = dh * ah[(size_t)j * N_HID + lane];
        }
        __syncthreads();

        if (lane < N_EMB) {
            float o = 0.f;
            const float4* trow = (const float4*)tbuf[wave];
            const float4* wrow = (const float4*)WfcT[lane];
            #pragma unroll
            for (int c = 0; c < 15; ++c) {
                float4 tv = trow[c];
                float4 wv = wrow[c];
                o = fmaf(tv.x, wv.x, o);
                o = fmaf(tv.y, wv.y, o);
                o = fmaf(tv.z, wv.z, o);
                o = fmaf(tv.w, wv.w, o);
            }
            o = fast_tanh(o);
            const int ie = active ? mi[e] : -1;
            if (ie != cur_i) {
                if (cur_i >= 0)
                    atomicAdd(&out[(size_t)cur_i * N_EMB + lane], acc);
                acc = 0.f;
                cur_i = ie;
            }
            if (active) acc += o;
        }
    }
    if (lane < N_EMB && cur_i >= 0)
        atomicAdd(&out[(size_t)cur_i * N_EMB + lane], acc);
}

extern "C" void kernel_launch(void* const* d_in, const int* in_sizes, int n_in,
                              void* d_out, int out_size, void* d_ws, size_t ws_size,
                              hipStream_t stream) {
    const float* af   = (const float*)d_in[0];
    const float* dist = (const float*)d_in[1];
    const int*   mi   = (const int*)d_in[2];
    const int*   mj   = (const int*)d_in[3];
    const float* W_cf = (const float*)d_in[4];
    const float* W_df = (const float*)d_in[5];
    const float* W_fc = (const float*)d_in[6];
    const float* b_cf = (const float*)d_in[7];
    const float* b_df = (const float*)d_in[8];
    float* out = (float*)d_out;
    float* ah  = (float*)d_ws;   // N_ATOMS * N_HID floats = 24 MB

    atom_kernel<<<N_ATOMS / WPB, 256, 0, stream>>>(af, W_cf, W_fc, b_cf, b_df, ah, out);
    edge_kernel<<<EBLOCKS, 256, 0, stream>>>(dist, mi, mj, W_df, W_fc, b_df, ah, out);
}

// Round 2
// 422.938 us; speedup vs baseline: 4.5628x; 4.5628x over previous
//
#include <hip/hip_runtime.h>
#include <hip/hip_bf16.h>

#define N_ATOMS 100000
#define N_PAIRS 2000000
#define N_EMB 30
#define N_DIST 100
#define N_HID 60

#define TE 64                       // edges per tile
#define NTILES (N_PAIRS / TE)       // 31250 exact
#define EBLOCKS 768                 // 3 blocks/CU resident

typedef short bf16x8 __attribute__((ext_vector_type(8)));
typedef float f32x4 __attribute__((ext_vector_type(4)));

__device__ __forceinline__ ushort f2bf(float f) {
    __hip_bfloat16 h = __float2bfloat16(f);
    return __builtin_bit_cast(ushort, h);
}
__device__ __forceinline__ float bf2f(ushort u) {
    __hip_bfloat16 h = __builtin_bit_cast(__hip_bfloat16, u);
    return __bfloat162float(h);
}
__device__ __forceinline__ float fast_tanh(float x) {
    float e = __expf(2.0f * x);
    return 1.0f - 2.0f / (e + 1.0f);
}

// ---------------- Kernel A: per-atom hidden + output init ----------------
__global__ __launch_bounds__(256) void atom_kernel(
    const float* __restrict__ af, const float* __restrict__ W_cf,
    const float* __restrict__ W_fc, const float* __restrict__ b_cf,
    const float* __restrict__ b_df, float* __restrict__ ah_out,
    float* __restrict__ out)
{
    __shared__ __align__(16) float ah_lds[4][N_HID];
    const int wave = threadIdx.x >> 6;
    const int lane = threadIdx.x & 63;
    const int n = blockIdx.x * 4 + wave;

    float ahv = 0.f;
    if (lane < N_HID) {
        ahv = b_cf[lane];
        #pragma unroll
        for (int k = 0; k < N_EMB; ++k)
            ahv = fmaf(af[(size_t)n * N_EMB + k], W_cf[k * N_HID + lane], ahv);
        ah_out[(size_t)n * N_HID + lane] = ahv;
        ah_lds[wave][lane] = ahv * b_df[lane];
    }
    __syncthreads();
    if (lane < N_EMB) {
        float s = 0.f;
        #pragma unroll
        for (int h = 0; h < N_HID; ++h)
            s = fmaf(ah_lds[wave][h], W_fc[h * N_EMB + lane], s);
        out[(size_t)n * N_EMB + lane] =
            af[(size_t)n * N_EMB + lane] - fast_tanh(s);
    }
}

// ---------------- Kernel B: fused MFMA edge pipeline ----------------
// Per 64-edge tile:
//  stage1: DH = dist_bf16 @ (Wdf_hi + Wdf_lo) + b_df   (wave w owns hid slice [16w,16w+16))
//  t      = DH * ah[mj[e]]  -> bf16 -> T_lds
//  stage2: S = tanh(T @ (Wfc_hi + Wfc_lo))              (wave w owns edge slice [16w,16w+16))
//  scan   : running segment-sum per (atom, f), atomic flush on boundary
__global__ __launch_bounds__(256, 3) void edge_kernel(
    const float* __restrict__ dist,
    const int* __restrict__ mi, const int* __restrict__ mj,
    const float* __restrict__ W_df, const float* __restrict__ W_fc,
    const float* __restrict__ b_df, const float* __restrict__ ah,
    float* out)
{
    // A_lds: 64 edges x 128 K (bf16), row stride 136 (272B -> conflict-free b128)
    __shared__ ushort A_lds[TE * 136];        // 17408 B
    __shared__ ushort T_lds[TE * 72];         // 64 x 64 pad 72 -> 9216 B
    __shared__ float  S_lds[4][16][33];       // 8448 B
    __shared__ int    mis[TE], mjs[TE];       // 512 B

    const int tid = threadIdx.x;
    const int wv = tid >> 6, lane = tid & 63;
    const int l4 = lane >> 4, ln = lane & 15;

    // ---- one-time: weight fragments (hi/lo split) into registers ----
    const int hb = wv * 16;
    const int h1 = hb + ln;                   // stage-1 output col (hid) for this lane
    bf16x8 wdf_hi[4], wdf_lo[4];              // [kstep], B-frag: k=(l4*8+i), n=h1
    #pragma unroll
    for (int ks = 0; ks < 4; ++ks) {
        #pragma unroll
        for (int i = 0; i < 8; ++i) {
            int k = ks * 32 + l4 * 8 + i;
            float f = (k < N_DIST && h1 < N_HID) ? W_df[k * N_HID + h1] : 0.f;
            ushort hi = f2bf(f);
            wdf_hi[ks][i] = (short)hi;
            wdf_lo[ks][i] = (short)f2bf(f - bf2f(hi));
        }
    }
    bf16x8 wfc_hi[2][2], wfc_lo[2][2];        // [nf][kstep]
    #pragma unroll
    for (int nf = 0; nf < 2; ++nf) {
        #pragma unroll
        for (int ks = 0; ks < 2; ++ks) {
            #pragma unroll
            for (int i = 0; i < 8; ++i) {
                int k = ks * 32 + l4 * 8 + i;
                int n = nf * 16 + ln;
                float f = (k < N_HID && n < N_EMB) ? W_fc[k * N_EMB + n] : 0.f;
                ushort hi = f2bf(f);
                wfc_hi[nf][ks][i] = (short)hi;
                wfc_lo[nf][ks][i] = (short)f2bf(f - bf2f(hi));
            }
        }
    }
    const float bdf1 = (h1 < N_HID) ? b_df[h1] : 0.f;

    // zero A_lds pad columns [100..136) once; never rewritten
    for (int idx = tid; idx < TE * 36; idx += 256) {
        int r = idx / 36, c = 100 + idx % 36;
        A_lds[r * 136 + c] = 0;
    }

    // running segment state (lanes 0..29 of each wave; persists across tiles)
    float acc = 0.f;
    int cur_i = -1;

    const int t0 = (int)(((long long)blockIdx.x * NTILES) / EBLOCKS);
    const int t1 = (int)(((long long)(blockIdx.x + 1) * NTILES) / EBLOCKS);

    for (int t = t0; t < t1; ++t) {
        const int e0 = t * TE;
        __syncthreads();   // protect A_lds/T_lds/mis from previous tile readers

        // ---- stage dist tile: 64 rows x 100 f32 -> bf16 A_lds ----
        const float4* src = (const float4*)(dist + (size_t)e0 * N_DIST);
        for (int idx = tid; idx < TE * 25; idx += 256) {
            int r = idx / 25, c = idx % 25;
            float4 v = src[idx];
            ushort4 pk;
            pk.x = f2bf(v.x); pk.y = f2bf(v.y); pk.z = f2bf(v.z); pk.w = f2bf(v.w);
            *(ushort4*)&A_lds[r * 136 + c * 4] = pk;
        }
        if (tid < TE) { mis[tid] = mi[e0 + tid]; mjs[tid] = mj[e0 + tid]; }
        __syncthreads();

        // ---- gather ah (issued before MFMA1 to hide L3 latency) ----
        float ahg[4][4];
        #pragma unroll
        for (int m = 0; m < 4; ++m) {
            #pragma unroll
            for (int r = 0; r < 4; ++r) {
                int el = 16 * m + l4 * 4 + r;
                int j = mjs[el];
                ahg[m][r] = (h1 < N_HID) ? ah[(size_t)j * N_HID + h1] : 0.f;
            }
        }

        // ---- stage-1 MFMA: all 64 edges x this wave's 16 hids ----
        f32x4 acc1[4] = {{0,0,0,0},{0,0,0,0},{0,0,0,0},{0,0,0,0}};
        #pragma unroll
        for (int ks = 0; ks < 4; ++ks) {
            #pragma unroll
            for (int m = 0; m < 4; ++m) {
                bf16x8 a = *(const bf16x8*)&A_lds[(16 * m + ln) * 136 + ks * 32 + l4 * 8];
                acc1[m] = __builtin_amdgcn_mfma_f32_16x16x32_bf16(a, wdf_hi[ks], acc1[m], 0, 0, 0);
                acc1[m] = __builtin_amdgcn_mfma_f32_16x16x32_bf16(a, wdf_lo[ks], acc1[m], 0, 0, 0);
            }
        }

        // ---- t = (dh + b_df) * ah -> bf16 -> T_lds ----
        #pragma unroll
        for (int m = 0; m < 4; ++m) {
            #pragma unroll
            for (int r = 0; r < 4; ++r) {
                int row = 16 * m + l4 * 4 + r;
                float tv = (acc1[m][r] + bdf1) * ahg[m][r];
                T_lds[row * 72 + h1] = (h1 < N_HID) ? f2bf(tv) : (ushort)0;
            }
        }
        __syncthreads();

        // ---- stage-2 MFMA: this wave's 16 edges x 32 f (30 used) ----
        f32x4 acc2[2] = {{0,0,0,0},{0,0,0,0}};
        #pragma unroll
        for (int ks = 0; ks < 2; ++ks) {
            bf16x8 a2 = *(const bf16x8*)&T_lds[(16 * wv + ln) * 72 + ks * 32 + l4 * 8];
            #pragma unroll
            for (int nf = 0; nf < 2; ++nf) {
                acc2[nf] = __builtin_amdgcn_mfma_f32_16x16x32_bf16(a2, wfc_hi[nf][ks], acc2[nf], 0, 0, 0);
                acc2[nf] = __builtin_amdgcn_mfma_f32_16x16x32_bf16(a2, wfc_lo[nf][ks], acc2[nf], 0, 0, 0);
            }
        }
        #pragma unroll
        for (int nf = 0; nf < 2; ++nf) {
            #pragma unroll
            for (int r = 0; r < 4; ++r)
                S_lds[wv][l4 * 4 + r][nf * 16 + ln] = fast_tanh(acc2[nf][r]);
        }

        // ---- segment scan over this wave's 16 edges (same-wave LDS, in-order) ----
        if (lane < N_EMB) {
            #pragma unroll 1
            for (int il = 0; il < 16; ++il) {
                int ia = mis[wv * 16 + il];
                float v = S_lds[wv][il][lane];
                if (ia != cur_i) {
                    if (cur_i >= 0) atomicAdd(&out[(size_t)cur_i * N_EMB + lane], acc);
                    acc = 0.f;
                    cur_i = ia;
                }
                acc += v;
            }
        }
    }
    if (lane < N_EMB && cur_i >= 0)
        atomicAdd(&out[(size_t)cur_i * N_EMB + lane], acc);
}

extern "C" void kernel_launch(void* const* d_in, const int* in_sizes, int n_in,
                              void* d_out, int out_size, void* d_ws, size_t ws_size,
                              hipStream_t stream) {
    const float* af   = (const float*)d_in[0];
    const float* dist = (const float*)d_in[1];
    const int*   mi   = (const int*)d_in[2];
    const int*   mj   = (const int*)d_in[3];
    const float* W_cf = (const float*)d_in[4];
    const float* W_df = (const float*)d_in[5];
    const float* W_fc = (const float*)d_in[6];
    const float* b_cf = (const float*)d_in[7];
    const float* b_df = (const float*)d_in[8];
    float* out = (float*)d_out;
    float* ah  = (float*)d_ws;   // N_ATOMS * N_HID floats = 24 MB

    atom_kernel<<<N_ATOMS / 4, 256, 0, stream>>>(af, W_cf, W_fc, b_cf, b_df, ah, out);
    edge_kernel<<<EBLOCKS, 256, 0, stream>>>(dist, mi, mj, W_df, W_fc, b_df, ah, out);
}

// Round 3
// 311.443 us; speedup vs baseline: 6.1962x; 1.3580x over previous
//
#include <hip/hip_runtime.h>
#include <hip/hip_bf16.h>

#define N_ATOMS 100000
#define N_PAIRS 2000000
#define N_EMB 30
#define N_DIST 100
#define N_HID 60

#define TE 64                       // edges per tile
#define NTILES (N_PAIRS / TE)       // 31250 exact
#define EBLOCKS 768                 // 3 blocks/CU resident

typedef short bf16x8 __attribute__((ext_vector_type(8)));
typedef float f32x4 __attribute__((ext_vector_type(4)));

__device__ __forceinline__ ushort f2bf(float f) {
    __hip_bfloat16 h = __float2bfloat16(f);
    return __builtin_bit_cast(ushort, h);
}
__device__ __forceinline__ float bf2f(ushort u) {
    __hip_bfloat16 h = __builtin_bit_cast(__hip_bfloat16, u);
    return __bfloat162float(h);
}
__device__ __forceinline__ float fast_tanh(float x) {
    float e = __expf(2.0f * x);
    return 1.0f - 2.0f / (e + 1.0f);
}

// ---------------- Kernel A: per-atom hidden + output init ----------------
__global__ __launch_bounds__(256) void atom_kernel(
    const float* __restrict__ af, const float* __restrict__ W_cf,
    const float* __restrict__ W_fc, const float* __restrict__ b_cf,
    const float* __restrict__ b_df, float* __restrict__ ah_out,
    float* __restrict__ out)
{
    __shared__ __align__(16) float ah_lds[4][N_HID];
    const int wave = threadIdx.x >> 6;
    const int lane = threadIdx.x & 63;
    const int n = blockIdx.x * 4 + wave;

    float ahv = 0.f;
    if (lane < N_HID) {
        ahv = b_cf[lane];
        #pragma unroll
        for (int k = 0; k < N_EMB; ++k)
            ahv = fmaf(af[(size_t)n * N_EMB + k], W_cf[k * N_HID + lane], ahv);
        ah_out[(size_t)n * N_HID + lane] = ahv;
        ah_lds[wave][lane] = ahv * b_df[lane];
    }
    __syncthreads();
    if (lane < N_EMB) {
        float s = 0.f;
        #pragma unroll
        for (int h = 0; h < N_HID; ++h)
            s = fmaf(ah_lds[wave][h], W_fc[h * N_EMB + lane], s);
        out[(size_t)n * N_EMB + lane] =
            af[(size_t)n * N_EMB + lane] - fast_tanh(s);
    }
}

// ---------------- Kernel B: fused MFMA edge pipeline, dbuf + selector-MFMA ----------------
__global__ __launch_bounds__(256, 3) void edge_kernel(
    const float* __restrict__ dist,
    const int* __restrict__ mi, const int* __restrict__ mj,
    const float* __restrict__ W_df, const float* __restrict__ W_fc,
    const float* __restrict__ b_df, const float* __restrict__ ah,
    float* out)
{
    __shared__ ushort A_lds[2][TE * 136];     // 34816 B (double-buffered dist tile, bf16)
    __shared__ ushort T_lds[TE * 72];         // 9216 B
    __shared__ ushort S_lds[32 * 72];         // 4608 B  (S^T: [f][edge], stride 72)
    __shared__ int    mis[2][TE], mjs[2][TE]; // 1024 B
    __shared__ int    seg_lds[TE];            // 256 B (local segment id per edge)
    __shared__ int    seg_atom[TE];           // 256 B (local segment id -> atom)

    const int tid = threadIdx.x;
    const int wv = tid >> 6, lane = tid & 63;
    const int l4 = lane >> 4, ln = lane & 15;
    const int h1 = wv * 16 + ln;              // stage-1 hid col for this lane

    // ---- one-time weight fragments ----
    bf16x8 wdf_hi[4], wdf_lo[4];              // B-frag: k = ks*32 + l4*8 + i, n = h1
    #pragma unroll
    for (int ks = 0; ks < 4; ++ks) {
        #pragma unroll
        for (int i = 0; i < 8; ++i) {
            int k = ks * 32 + l4 * 8 + i;
            float f = (k < N_DIST && h1 < N_HID) ? W_df[k * N_HID + h1] : 0.f;
            ushort hi = f2bf(f);
            wdf_hi[ks][i] = (short)hi;
            wdf_lo[ks][i] = (short)f2bf(f - bf2f(hi));
        }
    }
    bf16x8 wfc[2][2];                         // [nf][ks], single bf16
    #pragma unroll
    for (int nf = 0; nf < 2; ++nf) {
        #pragma unroll
        for (int ks = 0; ks < 2; ++ks) {
            #pragma unroll
            for (int i = 0; i < 8; ++i) {
                int k = ks * 32 + l4 * 8 + i;
                int n = nf * 16 + ln;
                float f = (k < N_HID && n < N_EMB) ? W_fc[k * N_EMB + n] : 0.f;
                wfc[nf][ks][i] = (short)f2bf(f);
            }
        }
    }
    const float bdf1 = (h1 < N_HID) ? b_df[h1] : 0.f;

    // zero A pad columns [100..136) in both buffers (never rewritten)
    for (int idx = tid; idx < 2 * TE * 36; idx += 256) {
        int b = idx / (TE * 36), rem = idx % (TE * 36);
        int r = rem / 36, c = 100 + rem % 36;
        A_lds[b][r * 136 + c] = 0;
    }

    const int t0 = (int)(((long long)blockIdx.x * NTILES) / EBLOCKS);
    const int t1 = (int)(((long long)(blockIdx.x + 1) * NTILES) / EBLOCKS);

    f32x4 pf[7];
    int pmi = 0, pmj = 0;

    auto stage_issue = [&](int t) {
        const f32x4* src = (const f32x4*)(dist + (size_t)t * TE * N_DIST);
        #pragma unroll
        for (int k = 0; k < 6; ++k)
            pf[k] = __builtin_nontemporal_load(&src[k * 256 + tid]);
        if (tid < 64) {
            pf[6] = __builtin_nontemporal_load(&src[6 * 256 + tid]);
            pmi = mi[t * TE + tid];
            pmj = mj[t * TE + tid];
        }
    };
    auto stage_write = [&](int buf) {
        #pragma unroll
        for (int k = 0; k < 7; ++k) {
            int idx = k * 256 + tid;
            if (k < 6 || tid < 64) {
                int r = idx / 25, c = idx % 25;
                f32x4 v = pf[k];
                ushort4 pk2;
                pk2.x = f2bf(v[0]); pk2.y = f2bf(v[1]);
                pk2.z = f2bf(v[2]); pk2.w = f2bf(v[3]);
                *(ushort4*)&A_lds[buf][r * 136 + c * 4] = pk2;
            }
        }
        if (tid < 64) { mis[buf][tid] = pmi; mjs[buf][tid] = pmj; }
    };

    // prologue: stage tile t0 into buffer 0
    stage_issue(t0);
    stage_write(0);
    __syncthreads();

    int cur = 0;
    for (int t = t0; t < t1; ++t) {
        const bool hasnext = (t + 1 < t1);
        if (hasnext) stage_issue(t + 1);      // async: lands before stage_write below

        // gather ah rows for this tile (hidden under MFMA1)
        float ahg[4][4];
        #pragma unroll
        for (int m = 0; m < 4; ++m) {
            #pragma unroll
            for (int r = 0; r < 4; ++r) {
                int el = 16 * m + l4 * 4 + r;
                int j = mjs[cur][el];
                ahg[m][r] = (h1 < N_HID) ? ah[(size_t)j * N_HID + h1] : 0.f;
            }
        }

        // ---- stage-1 MFMA: 64 edges x 16 hids (hi/lo split) ----
        f32x4 acc1[4] = {{0,0,0,0},{0,0,0,0},{0,0,0,0},{0,0,0,0}};
        #pragma unroll
        for (int ks = 0; ks < 4; ++ks) {
            #pragma unroll
            for (int m = 0; m < 4; ++m) {
                bf16x8 a = *(const bf16x8*)&A_lds[cur][(16 * m + ln) * 136 + ks * 32 + l4 * 8];
                acc1[m] = __builtin_amdgcn_mfma_f32_16x16x32_bf16(a, wdf_hi[ks], acc1[m], 0, 0, 0);
                acc1[m] = __builtin_amdgcn_mfma_f32_16x16x32_bf16(a, wdf_lo[ks], acc1[m], 0, 0, 0);
            }
        }

        __syncthreads();   // B1: prev tile's readers of T_lds/S_lds are done

        // ---- t = (dh + b_df) * ah -> bf16 -> T_lds ----
        #pragma unroll
        for (int m = 0; m < 4; ++m) {
            #pragma unroll
            for (int r = 0; r < 4; ++r) {
                int row = 16 * m + l4 * 4 + r;
                float tv = (acc1[m][r] + bdf1) * ahg[m][r];
                T_lds[row * 72 + h1] = (h1 < N_HID) ? f2bf(tv) : (ushort)0;
            }
        }
        __syncthreads();   // B2: T ready

        // ---- stage-2 MFMA: 16 edges x 32 f ----
        f32x4 acc2[2] = {{0,0,0,0},{0,0,0,0}};
        #pragma unroll
        for (int ks = 0; ks < 2; ++ks) {
            bf16x8 a2 = *(const bf16x8*)&T_lds[(16 * wv + ln) * 72 + ks * 32 + l4 * 8];
            #pragma unroll
            for (int nf = 0; nf < 2; ++nf)
                acc2[nf] = __builtin_amdgcn_mfma_f32_16x16x32_bf16(a2, wfc[nf][ks], acc2[nf], 0, 0, 0);
        }
        // tanh -> S^T (bf16) ; rows f>=30 are exact zeros (wfc zero-padded)
        #pragma unroll
        for (int nf = 0; nf < 2; ++nf) {
            #pragma unroll
            for (int r = 0; r < 4; ++r) {
                int f = nf * 16 + ln;
                int e = 16 * wv + l4 * 4 + r;
                S_lds[f * 72 + e] = f2bf(fast_tanh(acc2[nf][r]));
            }
        }

        // write next tile's A while S settles
        if (hasnext) stage_write(cur ^ 1);

        __syncthreads();   // B3: S ready, next A ready

        // ---- per-tile segment metadata (each wave redundantly, identical values) ----
        int m_e = mis[cur][lane];
        int prevv = __shfl_up(m_e, 1);
        bool changed = (lane > 0) && (m_e != prevv);
        unsigned long long bmask = __ballot(changed);
        int segl = __popcll(bmask & ((2ull << lane) - 1ull));
        if (lane == 0 || changed) seg_atom[segl] = m_e;
        seg_lds[lane] = segl;
        int nseg = __popcll(bmask) + 1;

        // ---- selector MFMA: C[seg][f] = sel[seg][e] @ S[e][f] ----
        int myseg = 16 * wv + ln;
        bf16x8 sfr[2];
        #pragma unroll
        for (int ks = 0; ks < 2; ++ks) {
            const int* sp = &seg_lds[ks * 32 + l4 * 8];
            #pragma unroll
            for (int i = 0; i < 8; ++i)
                sfr[ks][i] = (sp[i] == myseg) ? (short)0x3F80 : (short)0;
        }
        f32x4 acc3[2] = {{0,0,0,0},{0,0,0,0}};
        #pragma unroll
        for (int ks = 0; ks < 2; ++ks) {
            #pragma unroll
            for (int nf = 0; nf < 2; ++nf) {
                bf16x8 b = *(const bf16x8*)&S_lds[(nf * 16 + ln) * 72 + ks * 32 + l4 * 8];
                acc3[nf] = __builtin_amdgcn_mfma_f32_16x16x32_bf16(sfr[ks], b, acc3[nf], 0, 0, 0);
            }
        }
        // ---- flush: one atomicAdd per (present segment, f) ----
        #pragma unroll
        for (int nf = 0; nf < 2; ++nf) {
            #pragma unroll
            for (int r = 0; r < 4; ++r) {
                int gs = 16 * wv + l4 * 4 + r;
                int f = nf * 16 + ln;
                if (gs < nseg && f < N_EMB) {
                    int atomId = seg_atom[gs];
                    atomicAdd(&out[(size_t)atomId * N_EMB + f], acc3[nf][r]);
                }
            }
        }
        cur ^= 1;
    }
}

extern "C" void kernel_launch(void* const* d_in, const int* in_sizes, int n_in,
                              void* d_out, int out_size, void* d_ws, size_t ws_size,
                              hipStream_t stream) {
    const float* af   = (const float*)d_in[0];
    const float* dist = (const float*)d_in[1];
    const int*   mi   = (const int*)d_in[2];
    const int*   mj   = (const int*)d_in[3];
    const float* W_cf = (const float*)d_in[4];
    const float* W_df = (const float*)d_in[5];
    const float* W_fc = (const float*)d_in[6];
    const float* b_cf = (const float*)d_in[7];
    const float* b_df = (const float*)d_in[8];
    float* out = (float*)d_out;
    float* ah  = (float*)d_ws;   // N_ATOMS * N_HID floats = 24 MB

    atom_kernel<<<N_ATOMS / 4, 256, 0, stream>>>(af, W_cf, W_fc, b_cf, b_df, ah, out);
    edge_kernel<<<EBLOCKS, 256, 0, stream>>>(dist, mi, mj, W_df, W_fc, b_df, ah, out);
}